// Round 1
// baseline (1638.099 us; speedup 1.0000x reference)
//
#include <hip/hip_runtime.h>
#include <hip/hip_bf16.h>

#define T_TOK  2048
#define DIMSZ  2048
#define NEXP   32
#define INTERS 1024
#define SINTER 2048
#define NTOPK  6

typedef __bf16 bf16x8 __attribute__((ext_vector_type(8)));
typedef float  f32x4  __attribute__((ext_vector_type(4)));

__device__ __forceinline__ unsigned short f2b(float f) {
    __hip_bfloat16 h = __float2bfloat16(f);
    return __builtin_bit_cast(unsigned short, h);
}
__device__ __forceinline__ float b2f(unsigned short u) {
    __hip_bfloat16 h = __builtin_bit_cast(__hip_bfloat16, u);
    return __bfloat162float(h);
}

// ---------------- x -> bf16 ----------------
__global__ void cvt_kernel(const float4* __restrict__ src, ushort4* __restrict__ dst, int n4) {
    int i = blockIdx.x * blockDim.x + threadIdx.x;
    if (i < n4) {
        float4 v = src[i];
        ushort4 o;
        o.x = f2b(v.x); o.y = f2b(v.y); o.z = f2b(v.z); o.w = f2b(v.w);
        dst[i] = o;
    }
}

// ---------------- gating (fp32, must match reference ordering) ----------------
__global__ __launch_bounds__(64) void gate_kernel(
    const float* __restrict__ x, const float* __restrict__ gw,
    int* __restrict__ counts, int* __restrict__ toklist, float* __restrict__ wgts)
{
    int t = blockIdx.x;
    int lane = threadIdx.x;
    __shared__ float sc[NEXP];
    const float* xt = x + (size_t)t * DIMSZ;

    for (int e = 0; e < NEXP; ++e) {
        const float* we = gw + (size_t)e * DIMSZ;
        float s = 0.f;
        for (int d = lane; d < DIMSZ; d += 64) s += xt[d] * we[d];
        for (int off = 32; off > 0; off >>= 1) s += __shfl_down(s, off, 64);
        if (lane == 0) sc[e] = 1.f / (1.f + expf(-s));
    }
    __syncthreads();
    if (lane == 0) {
        // group scores = max of 4 within each of 8 groups
        float gsc[8];
        for (int g = 0; g < 8; ++g) {
            float m = sc[4 * g];
            for (int j = 1; j < 4; ++j) m = fmaxf(m, sc[4 * g + j]);
            gsc[g] = m;
        }
        // top-4 groups (greedy, lowest index wins ties like jax top_k)
        bool gsel[8] = {false, false, false, false, false, false, false, false};
        for (int it = 0; it < 4; ++it) {
            int bi = -1; float bv = -1e30f;
            for (int g = 0; g < 8; ++g)
                if (!gsel[g] && gsc[g] > bv) { bv = gsc[g]; bi = g; }
            gsel[bi] = true;
        }
        // top-6 experts among selected groups
        bool esel[NEXP];
        for (int e = 0; e < NEXP; ++e) esel[e] = false;
        int   idx[NTOPK];
        float w[NTOPK];
        float sum = 0.f;
        for (int it = 0; it < NTOPK; ++it) {
            int bi = -1; float bv = -1e30f;
            for (int e = 0; e < NEXP; ++e) {
                if (!gsel[e >> 2] || esel[e]) continue;
                if (sc[e] > bv) { bv = sc[e]; bi = e; }
            }
            esel[bi] = true; idx[it] = bi; w[it] = bv; sum += bv;
        }
        float scale = 2.5f / sum;
        for (int k = 0; k < NTOPK; ++k) {
            int e = idx[k];
            int s = atomicAdd(&counts[e], 1);
            toklist[e * T_TOK + s] = (t << 3) | k;
            wgts[e * T_TOK + s]   = w[k] * scale;
        }
    }
}

// ---------------- silu(g)*u elementwise ----------------
__global__ void silu_mul_kernel(const ushort4* __restrict__ g, const ushort4* __restrict__ u,
                                ushort4* __restrict__ h, int n4)
{
    int i = blockIdx.x * blockDim.x + threadIdx.x;
    if (i < n4) {
        ushort4 gv = g[i], uv = u[i];
        ushort4 o;
        float a;
        a = b2f(gv.x); o.x = f2b(a / (1.f + expf(-a)) * b2f(uv.x));
        a = b2f(gv.y); o.y = f2b(a / (1.f + expf(-a)) * b2f(uv.y));
        a = b2f(gv.z); o.z = f2b(a / (1.f + expf(-a)) * b2f(uv.z));
        a = b2f(gv.w); o.w = f2b(a / (1.f + expf(-a)) * b2f(uv.w));
        h[i] = o;
    }
}

// ---------------- GEMM: C[M,N] = A[M,K] @ Bt[N,K]^T  (bf16 MFMA) ----------------
// modes
#define SHARED_BF16 0  // C -> bf16 buffer (write)
#define SHARED_F32  1  // C -> f32 buffer (overwrite; used for d_out by shared fc2)
#define GROUP_FC1   2  // rows gathered via toklist; A row = t, C row = t*6+k, bf16 write
#define GROUP_FC2   3  // A row = t*6+k, atomicAdd wgt*acc into f32 C row t

template <int MODE>
__global__ __launch_bounds__(256) void gemm_bt(
    const unsigned short* __restrict__ A, const float* __restrict__ Bt,
    unsigned short* __restrict__ Cb, float* __restrict__ Cf,
    int N, int K, int M_fixed,
    const int* __restrict__ counts, const int* __restrict__ toklist,
    const float* __restrict__ wgts)
{
    constexpr int BM = 128, BN = 128, BK = 64, LDK = 72; // LDK padded: banks spread evenly
    __shared__ unsigned short As[BM * LDK];
    __shared__ unsigned short Bs[BN * LDK];
    __shared__ int   aRowS[BM];
    __shared__ int   cRowS[BM];
    __shared__ float cWS[BM];

    const int tid = threadIdx.x;
    const int e  = blockIdx.z;
    const int m0 = blockIdx.y * BM;
    const int n0 = blockIdx.x * BN;

    int M;
    const float* B;
    if constexpr (MODE == GROUP_FC1 || MODE == GROUP_FC2) {
        M = counts[e];
        if (m0 >= M) return;
        B = Bt + (size_t)e * N * K;
    } else {
        M = M_fixed;
        B = Bt;
    }

    if (tid < BM) {
        int r = m0 + tid;
        if constexpr (MODE == GROUP_FC1) {
            if (r < M) {
                int ent = toklist[e * T_TOK + r];
                int t = ent >> 3, k = ent & 7;
                aRowS[tid] = t; cRowS[tid] = t * NTOPK + k;
            } else { aRowS[tid] = 0; cRowS[tid] = -1; }
            cWS[tid] = 0.f;
        } else if constexpr (MODE == GROUP_FC2) {
            if (r < M) {
                int ent = toklist[e * T_TOK + r];
                int t = ent >> 3, k = ent & 7;
                aRowS[tid] = t * NTOPK + k; cRowS[tid] = t;
                cWS[tid] = wgts[e * T_TOK + r];
            } else { aRowS[tid] = 0; cRowS[tid] = -1; cWS[tid] = 0.f; }
        } else {
            aRowS[tid] = r; cRowS[tid] = (r < M) ? r : -1; cWS[tid] = 0.f;
        }
    }
    __syncthreads();

    f32x4 acc[4][4] = {};

    const int wave = tid >> 6;
    const int lane = tid & 63;
    const int wm = (wave >> 1) * 64;
    const int wn = (wave & 1) * 64;
    const int lm = lane & 15;
    const int quad = lane >> 4;

    for (int k0 = 0; k0 < K; k0 += BK) {
        // stage A: 128 rows x 64 bf16 (16B chunks), 256 thr x 4
        #pragma unroll
        for (int i = 0; i < 4; ++i) {
            int lin = tid + i * 256;
            int row = lin >> 3, cq = lin & 7;
            const unsigned short* src = A + (size_t)aRowS[row] * K + k0 + cq * 8;
            float4 v = *(const float4*)src;
            *(float4*)&As[row * LDK + cq * 8] = v;
        }
        // stage B: 128 rows x 64 f32 -> bf16, 256 thr x 8
        #pragma unroll
        for (int i = 0; i < 8; ++i) {
            int lin = tid + i * 256;
            int row = lin >> 4, cq = lin & 15;
            const float* src = B + (size_t)(n0 + row) * K + k0 + cq * 4;
            float4 v = *(const float4*)src;
            ushort4 o;
            o.x = f2b(v.x); o.y = f2b(v.y); o.z = f2b(v.z); o.w = f2b(v.w);
            *(ushort4*)&Bs[row * LDK + cq * 4] = o;
        }
        __syncthreads();
        #pragma unroll
        for (int kk = 0; kk < BK; kk += 32) {
            bf16x8 af[4], bfr[4];
            #pragma unroll
            for (int ti = 0; ti < 4; ++ti)
                af[ti] = *(const bf16x8*)&As[(wm + ti * 16 + lm) * LDK + kk + quad * 8];
            #pragma unroll
            for (int tj = 0; tj < 4; ++tj)
                bfr[tj] = *(const bf16x8*)&Bs[(wn + tj * 16 + lm) * LDK + kk + quad * 8];
            #pragma unroll
            for (int ti = 0; ti < 4; ++ti)
                #pragma unroll
                for (int tj = 0; tj < 4; ++tj)
                    acc[ti][tj] = __builtin_amdgcn_mfma_f32_16x16x32_bf16(
                        af[ti], bfr[tj], acc[ti][tj], 0, 0, 0);
        }
        __syncthreads();
    }

    // epilogue: D row = quad*4+reg, col = lane&15 (verified m89 mapping)
    #pragma unroll
    for (int ti = 0; ti < 4; ++ti) {
        #pragma unroll
        for (int r = 0; r < 4; ++r) {
            int lrow = wm + ti * 16 + quad * 4 + r;
            int cr = cRowS[lrow];
            if (cr < 0) continue;
            #pragma unroll
            for (int tj = 0; tj < 4; ++tj) {
                int nn = n0 + wn + tj * 16 + lm;
                float v = acc[ti][tj][r];
                if constexpr (MODE == SHARED_BF16 || MODE == GROUP_FC1)
                    Cb[(size_t)cr * N + nn] = f2b(v);
                else if constexpr (MODE == SHARED_F32)
                    Cf[(size_t)cr * N + nn] = v;
                else
                    atomicAdd(&Cf[(size_t)cr * N + nn], v * cWS[lrow]);
            }
        }
    }
}

extern "C" void kernel_launch(void* const* d_in, const int* in_sizes, int n_in,
                              void* d_out, int out_size, void* d_ws, size_t ws_size,
                              hipStream_t stream)
{
    const float* x   = (const float*)d_in[0];
    const float* gw  = (const float*)d_in[1];
    const float* w11 = (const float*)d_in[2];
    const float* w33 = (const float*)d_in[3];
    const float* w22 = (const float*)d_in[4];
    const float* sw1 = (const float*)d_in[5];
    const float* sw2 = (const float*)d_in[6];
    const float* sw3 = (const float*)d_in[7];
    float* out = (float*)d_out;

    char* ws = (char*)d_ws;
    size_t off = 0;
    auto alloc = [&](size_t b) { void* p = ws + off; off = (off + b + 255) & ~(size_t)255; return p; };
    int*            counts  = (int*)alloc(NEXP * 4);
    int*            toklist = (int*)alloc((size_t)NEXP * T_TOK * 4);
    float*          wgts    = (float*)alloc((size_t)NEXP * T_TOK * 4);
    unsigned short* xb      = (unsigned short*)alloc((size_t)T_TOK * DIMSZ * 2);
    unsigned short* g       = (unsigned short*)alloc((size_t)T_TOK * NTOPK * INTERS * 2);
    unsigned short* u       = (unsigned short*)alloc((size_t)T_TOK * NTOPK * INTERS * 2);
    unsigned short* gs      = (unsigned short*)alloc((size_t)T_TOK * SINTER * 2);
    unsigned short* us      = (unsigned short*)alloc((size_t)T_TOK * SINTER * 2);

    hipMemsetAsync(counts, 0, NEXP * 4, stream);

    int n4x = T_TOK * DIMSZ / 4;
    cvt_kernel<<<(n4x + 255) / 256, 256, 0, stream>>>((const float4*)x, (ushort4*)xb, n4x);

    gate_kernel<<<T_TOK, 64, 0, stream>>>(x, gw, counts, toklist, wgts);

    // shared expert: gs = x@sw1^T, us = x@sw3^T, hs = silu(gs)*us (in gs), out = hs@sw2^T
    gemm_bt<SHARED_BF16><<<dim3(SINTER / 128, T_TOK / 128, 1), 256, 0, stream>>>(
        xb, sw1, gs, nullptr, SINTER, DIMSZ, T_TOK, nullptr, nullptr, nullptr);
    gemm_bt<SHARED_BF16><<<dim3(SINTER / 128, T_TOK / 128, 1), 256, 0, stream>>>(
        xb, sw3, us, nullptr, SINTER, DIMSZ, T_TOK, nullptr, nullptr, nullptr);
    int n4s = T_TOK * SINTER / 4;
    silu_mul_kernel<<<(n4s + 255) / 256, 256, 0, stream>>>(
        (const ushort4*)gs, (const ushort4*)us, (ushort4*)gs, n4s);
    gemm_bt<SHARED_F32><<<dim3(DIMSZ / 128, T_TOK / 128, 1), 256, 0, stream>>>(
        gs, sw2, nullptr, out, DIMSZ, SINTER, T_TOK, nullptr, nullptr, nullptr);

    // routed experts: g = gather(x)@w11^T, u = gather(x)@w33^T, h = silu(g)*u (in g),
    // out += wgt * (h @ w22^T)
    gemm_bt<GROUP_FC1><<<dim3(INTERS / 128, T_TOK / 128, NEXP), 256, 0, stream>>>(
        xb, w11, g, nullptr, INTERS, DIMSZ, 0, counts, toklist, wgts);
    gemm_bt<GROUP_FC1><<<dim3(INTERS / 128, T_TOK / 128, NEXP), 256, 0, stream>>>(
        xb, w33, u, nullptr, INTERS, DIMSZ, 0, counts, toklist, wgts);
    int n4r = T_TOK * NTOPK * INTERS / 4;
    silu_mul_kernel<<<(n4r + 255) / 256, 256, 0, stream>>>(
        (const ushort4*)g, (const ushort4*)u, (ushort4*)g, n4r);
    gemm_bt<GROUP_FC2><<<dim3(DIMSZ / 128, T_TOK / 128, NEXP), 256, 0, stream>>>(
        g, w22, nullptr, out, DIMSZ, INTERS, 0, counts, toklist, wgts);
}

// Round 2
// 1305.567 us; speedup vs baseline: 1.2547x; 1.2547x over previous
//
#include <hip/hip_runtime.h>
#include <hip/hip_bf16.h>

#define T_TOK  2048
#define DIMSZ  2048
#define NEXP   32
#define INTERS 1024
#define SINTER 2048
#define NTOPK  6

typedef __bf16 bf16x8 __attribute__((ext_vector_type(8)));
typedef float  f32x4  __attribute__((ext_vector_type(4)));

__device__ __forceinline__ unsigned short f2b(float f) {
    __hip_bfloat16 h = __float2bfloat16(f);
    return __builtin_bit_cast(unsigned short, h);
}
__device__ __forceinline__ float b2f(unsigned short u) {
    __hip_bfloat16 h = __builtin_bit_cast(__hip_bfloat16, u);
    return __bfloat162float(h);
}

// ---------------- x -> bf16 ----------------
__global__ void cvt_kernel(const float4* __restrict__ src, ushort4* __restrict__ dst, int n4) {
    int i = blockIdx.x * blockDim.x + threadIdx.x;
    if (i < n4) {
        float4 v = src[i];
        ushort4 o;
        o.x = f2b(v.x); o.y = f2b(v.y); o.z = f2b(v.z); o.w = f2b(v.w);
        dst[i] = o;
    }
}

// ---------------- gate scores: scores[T,E] = sigmoid(x @ gw^T), fp32 ----------------
// 8 tokens x 32 experts per 256-thread block, K-chunked LDS staging.
#define SCT 8
#define SCK 128
__global__ __launch_bounds__(256) void gate_scores_kernel(
    const float* __restrict__ x, const float* __restrict__ gw, float* __restrict__ scores)
{
    __shared__ float xs[SCT * SCK];            // 8 x 128
    __shared__ float gs[NEXP * (SCK + 1)];     // 32 x 129 (pad: conflict-free)
    const int t0 = blockIdx.x * SCT;
    const int tid = threadIdx.x;
    const int tl = tid >> 5, e = tid & 31;
    float acc = 0.f;
    for (int k0 = 0; k0 < DIMSZ; k0 += SCK) {
        {   // xs: 1024 floats = 256 x float4
            int row = tid >> 5, d4 = tid & 31;
            *(float4*)&xs[row * SCK + d4 * 4] =
                *(const float4*)&x[(size_t)(t0 + row) * DIMSZ + k0 + d4 * 4];
        }
        #pragma unroll
        for (int i = 0; i < 4; ++i) {  // gs: 4096 floats = 256 x 4 x float4
            int lin = tid + i * 256;
            int row = lin >> 5, d4 = lin & 31;
            float4 v = *(const float4*)&gw[(size_t)row * DIMSZ + k0 + d4 * 4];
            float* dst = &gs[row * (SCK + 1) + d4 * 4];
            dst[0] = v.x; dst[1] = v.y; dst[2] = v.z; dst[3] = v.w;
        }
        __syncthreads();
        #pragma unroll 8
        for (int d = 0; d < SCK; ++d)
            acc += xs[tl * SCK + d] * gs[e * (SCK + 1) + d];
        __syncthreads();
    }
    scores[(size_t)(t0 + tl) * NEXP + e] = 1.f / (1.f + expf(-acc));
}

// ---------------- top-k routing (one thread per token) ----------------
__global__ __launch_bounds__(256) void topk_kernel(
    const float* __restrict__ scores,
    int* __restrict__ counts, int* __restrict__ toklist, float* __restrict__ wgts)
{
    int t = blockIdx.x * 256 + threadIdx.x;
    if (t >= T_TOK) return;
    float sc[NEXP];
    #pragma unroll
    for (int e = 0; e < NEXP; ++e) sc[e] = scores[(size_t)t * NEXP + e];

    float gsc[8];
    #pragma unroll
    for (int g = 0; g < 8; ++g) {
        float m = sc[4 * g];
        #pragma unroll
        for (int j = 1; j < 4; ++j) m = fmaxf(m, sc[4 * g + j]);
        gsc[g] = m;
    }
    bool gsel[8] = {false, false, false, false, false, false, false, false};
    for (int it = 0; it < 4; ++it) {
        int bi = -1; float bv = -1e30f;
        #pragma unroll
        for (int g = 0; g < 8; ++g)
            if (!gsel[g] && gsc[g] > bv) { bv = gsc[g]; bi = g; }
        gsel[bi] = true;
    }
    bool esel[NEXP];
    #pragma unroll
    for (int e = 0; e < NEXP; ++e) esel[e] = false;
    int   idx[NTOPK];
    float w[NTOPK];
    float sum = 0.f;
    for (int it = 0; it < NTOPK; ++it) {
        int bi = -1; float bv = -1e30f;
        #pragma unroll
        for (int e = 0; e < NEXP; ++e) {
            if (!gsel[e >> 2] || esel[e]) continue;
            if (sc[e] > bv) { bv = sc[e]; bi = e; }
        }
        esel[bi] = true; idx[it] = bi; w[it] = bv; sum += bv;
    }
    float scale = 2.5f / sum;
    for (int k = 0; k < NTOPK; ++k) {
        int e = idx[k];
        int s = atomicAdd(&counts[e], 1);
        toklist[e * T_TOK + s] = (t << 3) | k;
        wgts[e * T_TOK + s]   = w[k] * scale;
    }
}

// ---------------- fused fc1: H = silu(A@B1^T) * (A@B2^T), bf16 out ----------------
template <bool GROUPED>
__global__ __launch_bounds__(256) void fc1_fused(
    const unsigned short* __restrict__ A,
    const float* __restrict__ B1t, const float* __restrict__ B2t,
    unsigned short* __restrict__ H, int N, int K, int M_fixed,
    const int* __restrict__ counts, const int* __restrict__ toklist)
{
    constexpr int BM = 128, BN = 128, BK = 64, LDK = 72;
    __shared__ unsigned short As[BM * LDK];
    __shared__ unsigned short B1s[BN * LDK];
    __shared__ unsigned short B2s[BN * LDK];
    __shared__ int aRowS[BM];
    __shared__ int cRowS[BM];

    const int tid = threadIdx.x;
    const int e  = blockIdx.z;
    const int m0 = blockIdx.y * BM;
    const int n0 = blockIdx.x * BN;

    int M;
    const float *B1, *B2;
    if constexpr (GROUPED) {
        M = counts[e];
        if (m0 >= M) return;
        B1 = B1t + (size_t)e * N * K;
        B2 = B2t + (size_t)e * N * K;
    } else {
        M = M_fixed; B1 = B1t; B2 = B2t;
    }

    if (tid < BM) {
        int r = m0 + tid;
        if constexpr (GROUPED) {
            if (r < M) {
                int ent = toklist[e * T_TOK + r];
                int t = ent >> 3, k = ent & 7;
                aRowS[tid] = t; cRowS[tid] = t * NTOPK + k;
            } else { aRowS[tid] = 0; cRowS[tid] = -1; }
        } else {
            aRowS[tid] = r; cRowS[tid] = (r < M) ? r : -1;
        }
    }
    __syncthreads();

    f32x4 acc1[4][4] = {};
    f32x4 acc2[4][4] = {};

    const int wave = tid >> 6;
    const int lane = tid & 63;
    const int wm = (wave >> 1) * 64;
    const int wn = (wave & 1) * 64;
    const int lm = lane & 15;
    const int quad = lane >> 4;

    for (int k0 = 0; k0 < K; k0 += BK) {
        #pragma unroll
        for (int i = 0; i < 4; ++i) {
            int lin = tid + i * 256;
            int row = lin >> 3, cq = lin & 7;
            const unsigned short* src = A + (size_t)aRowS[row] * K + k0 + cq * 8;
            *(float4*)&As[row * LDK + cq * 8] = *(const float4*)src;
        }
        #pragma unroll
        for (int i = 0; i < 8; ++i) {
            int lin = tid + i * 256;
            int row = lin >> 4, cq = lin & 15;
            size_t boff = (size_t)(n0 + row) * K + k0 + cq * 4;
            float4 v1 = *(const float4*)(B1 + boff);
            float4 v2 = *(const float4*)(B2 + boff);
            ushort4 o1, o2;
            o1.x = f2b(v1.x); o1.y = f2b(v1.y); o1.z = f2b(v1.z); o1.w = f2b(v1.w);
            o2.x = f2b(v2.x); o2.y = f2b(v2.y); o2.z = f2b(v2.z); o2.w = f2b(v2.w);
            *(ushort4*)&B1s[row * LDK + cq * 4] = o1;
            *(ushort4*)&B2s[row * LDK + cq * 4] = o2;
        }
        __syncthreads();
        #pragma unroll
        for (int kk = 0; kk < BK; kk += 32) {
            bf16x8 af[4], b1f[4], b2f[4];
            #pragma unroll
            for (int ti = 0; ti < 4; ++ti)
                af[ti] = *(const bf16x8*)&As[(wm + ti * 16 + lm) * LDK + kk + quad * 8];
            #pragma unroll
            for (int tj = 0; tj < 4; ++tj) {
                b1f[tj] = *(const bf16x8*)&B1s[(wn + tj * 16 + lm) * LDK + kk + quad * 8];
                b2f[tj] = *(const bf16x8*)&B2s[(wn + tj * 16 + lm) * LDK + kk + quad * 8];
            }
            #pragma unroll
            for (int ti = 0; ti < 4; ++ti)
                #pragma unroll
                for (int tj = 0; tj < 4; ++tj) {
                    acc1[ti][tj] = __builtin_amdgcn_mfma_f32_16x16x32_bf16(
                        af[ti], b1f[tj], acc1[ti][tj], 0, 0, 0);
                    acc2[ti][tj] = __builtin_amdgcn_mfma_f32_16x16x32_bf16(
                        af[ti], b2f[tj], acc2[ti][tj], 0, 0, 0);
                }
        }
        __syncthreads();
    }

    #pragma unroll
    for (int ti = 0; ti < 4; ++ti) {
        #pragma unroll
        for (int r = 0; r < 4; ++r) {
            int lrow = wm + ti * 16 + quad * 4 + r;
            int cr = cRowS[lrow];
            if (cr < 0) continue;
            #pragma unroll
            for (int tj = 0; tj < 4; ++tj) {
                int nn = n0 + wn + tj * 16 + lm;
                float g = acc1[ti][tj][r];
                float u = acc2[ti][tj][r];
                float h = g / (1.f + expf(-g)) * u;
                H[(size_t)cr * N + nn] = f2b(h);
            }
        }
    }
}

// ---------------- fc2 GEMM: C[M,N] = A[M,K] @ Bt[N,K]^T ----------------
#define SHARED_F32  1  // overwrite f32 C (d_out)
#define GROUP_FC2   3  // atomicAdd wgt*acc into f32 C row t

template <int MODE>
__global__ __launch_bounds__(256) void gemm_bt(
    const unsigned short* __restrict__ A, const float* __restrict__ Bt,
    float* __restrict__ Cf, int N, int K, int M_fixed,
    const int* __restrict__ counts, const int* __restrict__ toklist,
    const float* __restrict__ wgts)
{
    constexpr int BM = 128, BN = 128, BK = 64, LDK = 72;
    __shared__ unsigned short As[BM * LDK];
    __shared__ unsigned short Bs[BN * LDK];
    __shared__ int   aRowS[BM];
    __shared__ int   cRowS[BM];
    __shared__ float cWS[BM];

    const int tid = threadIdx.x;
    const int e  = blockIdx.z;
    const int m0 = blockIdx.y * BM;
    const int n0 = blockIdx.x * BN;

    int M;
    const float* B;
    if constexpr (MODE == GROUP_FC2) {
        M = counts[e];
        if (m0 >= M) return;
        B = Bt + (size_t)e * N * K;
    } else {
        M = M_fixed;
        B = Bt;
    }

    if (tid < BM) {
        int r = m0 + tid;
        if constexpr (MODE == GROUP_FC2) {
            if (r < M) {
                int ent = toklist[e * T_TOK + r];
                int t = ent >> 3, k = ent & 7;
                aRowS[tid] = t * NTOPK + k; cRowS[tid] = t;
                cWS[tid] = wgts[e * T_TOK + r];
            } else { aRowS[tid] = 0; cRowS[tid] = -1; cWS[tid] = 0.f; }
        } else {
            aRowS[tid] = r; cRowS[tid] = (r < M) ? r : -1; cWS[tid] = 0.f;
        }
    }
    __syncthreads();

    f32x4 acc[4][4] = {};

    const int wave = tid >> 6;
    const int lane = tid & 63;
    const int wm = (wave >> 1) * 64;
    const int wn = (wave & 1) * 64;
    const int lm = lane & 15;
    const int quad = lane >> 4;

    for (int k0 = 0; k0 < K; k0 += BK) {
        #pragma unroll
        for (int i = 0; i < 4; ++i) {
            int lin = tid + i * 256;
            int row = lin >> 3, cq = lin & 7;
            const unsigned short* src = A + (size_t)aRowS[row] * K + k0 + cq * 8;
            *(float4*)&As[row * LDK + cq * 8] = *(const float4*)src;
        }
        #pragma unroll
        for (int i = 0; i < 8; ++i) {
            int lin = tid + i * 256;
            int row = lin >> 4, cq = lin & 15;
            const float* src = B + (size_t)(n0 + row) * K + k0 + cq * 4;
            float4 v = *(const float4*)src;
            ushort4 o;
            o.x = f2b(v.x); o.y = f2b(v.y); o.z = f2b(v.z); o.w = f2b(v.w);
            *(ushort4*)&Bs[row * LDK + cq * 4] = o;
        }
        __syncthreads();
        #pragma unroll
        for (int kk = 0; kk < BK; kk += 32) {
            bf16x8 af[4], bfr[4];
            #pragma unroll
            for (int ti = 0; ti < 4; ++ti)
                af[ti] = *(const bf16x8*)&As[(wm + ti * 16 + lm) * LDK + kk + quad * 8];
            #pragma unroll
            for (int tj = 0; tj < 4; ++tj)
                bfr[tj] = *(const bf16x8*)&Bs[(wn + tj * 16 + lm) * LDK + kk + quad * 8];
            #pragma unroll
            for (int ti = 0; ti < 4; ++ti)
                #pragma unroll
                for (int tj = 0; tj < 4; ++tj)
                    acc[ti][tj] = __builtin_amdgcn_mfma_f32_16x16x32_bf16(
                        af[ti], bfr[tj], acc[ti][tj], 0, 0, 0);
        }
        __syncthreads();
    }

    #pragma unroll
    for (int ti = 0; ti < 4; ++ti) {
        #pragma unroll
        for (int r = 0; r < 4; ++r) {
            int lrow = wm + ti * 16 + quad * 4 + r;
            int cr = cRowS[lrow];
            if (cr < 0) continue;
            #pragma unroll
            for (int tj = 0; tj < 4; ++tj) {
                int nn = n0 + wn + tj * 16 + lm;
                float v = acc[ti][tj][r];
                if constexpr (MODE == SHARED_F32)
                    Cf[(size_t)cr * N + nn] = v;
                else
                    atomicAdd(&Cf[(size_t)cr * N + nn], v * cWS[lrow]);
            }
        }
    }
}

extern "C" void kernel_launch(void* const* d_in, const int* in_sizes, int n_in,
                              void* d_out, int out_size, void* d_ws, size_t ws_size,
                              hipStream_t stream)
{
    const float* x   = (const float*)d_in[0];
    const float* gw  = (const float*)d_in[1];
    const float* w11 = (const float*)d_in[2];
    const float* w33 = (const float*)d_in[3];
    const float* w22 = (const float*)d_in[4];
    const float* sw1 = (const float*)d_in[5];
    const float* sw2 = (const float*)d_in[6];
    const float* sw3 = (const float*)d_in[7];
    float* out = (float*)d_out;

    char* ws = (char*)d_ws;
    size_t off = 0;
    auto alloc = [&](size_t b) { void* p = ws + off; off = (off + b + 255) & ~(size_t)255; return p; };
    int*            counts  = (int*)alloc(NEXP * 4);
    int*            toklist = (int*)alloc((size_t)NEXP * T_TOK * 4);
    float*          wgts    = (float*)alloc((size_t)NEXP * T_TOK * 4);
    float*          scores  = (float*)alloc((size_t)T_TOK * NEXP * 4);
    unsigned short* xb      = (unsigned short*)alloc((size_t)T_TOK * DIMSZ * 2);
    unsigned short* h       = (unsigned short*)alloc((size_t)T_TOK * NTOPK * INTERS * 2);
    unsigned short* hs      = (unsigned short*)alloc((size_t)T_TOK * SINTER * 2);

    hipMemsetAsync(counts, 0, NEXP * 4, stream);

    int n4x = T_TOK * DIMSZ / 4;
    cvt_kernel<<<(n4x + 255) / 256, 256, 0, stream>>>((const float4*)x, (ushort4*)xb, n4x);

    gate_scores_kernel<<<T_TOK / SCT, 256, 0, stream>>>(x, gw, scores);
    topk_kernel<<<(T_TOK + 255) / 256, 256, 0, stream>>>(scores, counts, toklist, wgts);

    // shared expert: hs = silu(x@sw1^T)*(x@sw3^T), out = hs@sw2^T
    fc1_fused<false><<<dim3(SINTER / 128, T_TOK / 128, 1), 256, 0, stream>>>(
        xb, sw1, sw3, hs, SINTER, DIMSZ, T_TOK, nullptr, nullptr);
    gemm_bt<SHARED_F32><<<dim3(DIMSZ / 128, T_TOK / 128, 1), 256, 0, stream>>>(
        hs, sw2, out, DIMSZ, SINTER, T_TOK, nullptr, nullptr, nullptr);

    // routed experts: h = silu(gather(x)@w11^T)*(gather(x)@w33^T); out += wgt*(h@w22^T)
    fc1_fused<true><<<dim3(INTERS / 128, T_TOK / 128, NEXP), 256, 0, stream>>>(
        xb, w11, w33, h, INTERS, DIMSZ, 0, counts, toklist);
    gemm_bt<GROUP_FC2><<<dim3(DIMSZ / 128, T_TOK / 128, NEXP), 256, 0, stream>>>(
        h, w22, out, DIMSZ, INTERS, 0, counts, toklist, wgts);
}